// Round 1
// baseline (391.859 us; speedup 1.0000x reference)
//
#include <hip/hip_runtime.h>
#include <stdint.h>

typedef __attribute__((ext_vector_type(8))) __bf16 bf16x8;
typedef __attribute__((ext_vector_type(4))) float f32x4;
typedef __attribute__((ext_vector_type(4))) unsigned short us4;

__device__ __forceinline__ unsigned short f2b(float f){
  unsigned int u = __builtin_bit_cast(unsigned int, f);
  unsigned int r = (u + 0x7fffu + ((u >> 16) & 1u)) >> 16;
  return (unsigned short)r;
}
__device__ __forceinline__ float b2f(unsigned short h){
  unsigned int u = ((unsigned int)h) << 16;
  return __builtin_bit_cast(float, u);
}

#define KDIM 1024
#define NDIM 1024

// ---------------- prep kernels ----------------

__global__ void k_cast_bf16(const float* __restrict__ in, unsigned short* __restrict__ out, int n4){
  int i = blockIdx.x * 256 + threadIdx.x;
  if (i < n4){
    float4 v = ((const float4*)in)[i];
    us4 o; o.x = f2b(v.x); o.y = f2b(v.y); o.z = f2b(v.z); o.w = f2b(v.w);
    ((us4*)out)[i] = o;
  }
}

// out[b][c][r] = in[b][r][c], cast to bf16
__global__ void k_transpose_cast(const float* __restrict__ in, unsigned short* __restrict__ out,
                                 int rows, int cols, int total){
  int idx = blockIdx.x * 256 + threadIdx.x;
  if (idx >= total) return;
  int rc = rows * cols;
  int b = idx / rc, rem = idx - b * rc;
  int c = rem / rows, r = rem - c * rows;
  out[idx] = f2b(in[(size_t)b * rc + (size_t)r * cols + c]);
}

// h_q[r] = sum_n allh[n*128+r]*fwq[n];  g_q[n*128+r] = rwq[n]*h_q[r]   (same for k)
__global__ __launch_bounds__(128) void k_mix_qk(const unsigned short* __restrict__ allh,
    const float* __restrict__ fwq, const float* __restrict__ fwk,
    const float* __restrict__ rwq, const float* __restrict__ rwk,
    unsigned short* __restrict__ gq, unsigned short* __restrict__ gk){
  int bs = blockIdx.x; int r = threadIdx.x;
  const unsigned short* ah = allh + (size_t)bs * 1024;
  float hq = 0.f, hk = 0.f;
  float fq[8], fk[8], rq[8], rk[8];
  #pragma unroll
  for (int n = 0; n < 8; n++){ fq[n] = fwq[bs*8+n]; fk[n] = fwk[bs*8+n]; rq[n] = rwq[bs*8+n]; rk[n] = rwk[bs*8+n]; }
  #pragma unroll
  for (int n = 0; n < 8; n++){ float a = b2f(ah[n*128 + r]); hq += a * fq[n]; hk += a * fk[n]; }
  #pragma unroll
  for (int n = 0; n < 8; n++){
    gq[(size_t)bs*1024 + n*128 + r] = f2b(rq[n] * hq);
    gk[(size_t)bs*1024 + n*128 + r] = f2b(rk[n] * hk);
  }
}

__global__ __launch_bounds__(128) void k_mix_v(const unsigned short* __restrict__ allh,
    const float* __restrict__ fwv, const float* __restrict__ rwv,
    unsigned short* __restrict__ gv){
  int bs = blockIdx.x; int r = threadIdx.x;
  const unsigned short* ah = allh + (size_t)bs * 1024;
  float hv = 0.f;
  float fv[8], rv[8];
  #pragma unroll
  for (int n = 0; n < 8; n++){ fv[n] = fwv[bs*8+n]; rv[n] = rwv[bs*8+n]; }
  #pragma unroll
  for (int n = 0; n < 8; n++){ hv += b2f(ah[n*128 + r]) * fv[n]; }
  #pragma unroll
  for (int n = 0; n < 8; n++){ gv[(size_t)bs*1024 + n*128 + r] = f2b(rv[n] * hv); }
}

// Vt[(bh*64+dh)][s] = Vb[(b*2048+s)][h*64+dh]
__global__ void k_transpose_v(const unsigned short* __restrict__ Vb, unsigned short* __restrict__ Vt){
  int idx = blockIdx.x * 256 + threadIdx.x;
  int s = idx & 2047, row = idx >> 11;
  int bh = row >> 6, dh = row & 63, b = bh >> 4, h = bh & 15;
  Vt[idx] = Vb[((size_t)(b*2048 + s)) * 1024 + h*64 + dh];
}

// ---------------- GEMM: C[M,N] = A[M,K] @ Bt[N,K]^T, bf16 in, f32 acc ----------------

__device__ __forceinline__ void load_lds16(const void* g, void* l){
  __builtin_amdgcn_global_load_lds((const __attribute__((address_space(1))) unsigned int*)g,
                                   (__attribute__((address_space(3))) unsigned int*)l, 16, 0, 0);
}

template<int OUT_BF16>
__global__ __launch_bounds__(256) void k_gemm_bt3(
    const unsigned short* __restrict__ A0, const unsigned short* __restrict__ B0, void* __restrict__ C0,
    const unsigned short* __restrict__ A1, const unsigned short* __restrict__ B1, void* __restrict__ C1,
    const unsigned short* __restrict__ A2, const unsigned short* __restrict__ B2, void* __restrict__ C2)
{
  __shared__ unsigned short Al[2][128*32];
  __shared__ unsigned short Bl[2][128*32];
  int job = blockIdx.x >> 8;
  int bid = blockIdx.x & 255;
  const unsigned short* A  = job == 0 ? A0 : (job == 1 ? A1 : A2);
  const unsigned short* Bt = job == 0 ? B0 : (job == 1 ? B1 : B2);
  void* C = job == 0 ? C0 : (job == 1 ? C1 : C2);
  int bx = bid & 7, by = bid >> 3;
  int m0 = by * 128, n0 = bx * 128;
  int tid = threadIdx.x, wid = tid >> 6, lane = tid & 63, l15 = lane & 15, g = lane >> 4;
  int wr = wid >> 1, wc = wid & 1;

  auto stage = [&](int buf, int kt){
    #pragma unroll
    for (int i = 0; i < 2; i++){
      int c = i * 256 + tid;
      load_lds16(A + (size_t)(m0 + (c >> 2)) * KDIM + kt * 32 + (c & 3) * 8,
                 &Al[buf][(i * 256 + wid * 64) * 8]);
    }
    #pragma unroll
    for (int i = 0; i < 2; i++){
      int c = i * 256 + tid;
      load_lds16(Bt + (size_t)(n0 + (c >> 2)) * KDIM + kt * 32 + (c & 3) * 8,
                 &Bl[buf][(i * 256 + wid * 64) * 8]);
    }
  };

  f32x4 acc[4][4] = {};

  stage(0, 0);
  __syncthreads();
  int cur = 0;
  const int nk = KDIM / 32;
  for (int kt = 0; kt < nk; ++kt){
    if (kt + 1 < nk) stage(cur ^ 1, kt + 1);
    bf16x8 af[4], bfv[4];
    #pragma unroll
    for (int mi = 0; mi < 4; mi++)
      af[mi] = *(const bf16x8*)&Al[cur][(wr*64 + mi*16 + l15) * 32 + g * 8];
    #pragma unroll
    for (int ni = 0; ni < 4; ni++)
      bfv[ni] = *(const bf16x8*)&Bl[cur][(wc*64 + ni*16 + l15) * 32 + g * 8];
    #pragma unroll
    for (int mi = 0; mi < 4; mi++)
      #pragma unroll
      for (int ni = 0; ni < 4; ni++)
        acc[mi][ni] = __builtin_amdgcn_mfma_f32_16x16x32_bf16(af[mi], bfv[ni], acc[mi][ni], 0, 0, 0);
    __syncthreads();
    cur ^= 1;
  }

  #pragma unroll
  for (int mi = 0; mi < 4; mi++){
    #pragma unroll
    for (int reg = 0; reg < 4; reg++){
      int row = m0 + wr*64 + mi*16 + g*4 + reg;
      #pragma unroll
      for (int ni = 0; ni < 4; ni++){
        int col = n0 + wc*64 + ni*16 + l15;
        float v = acc[mi][ni][reg];
        if (OUT_BF16) ((unsigned short*)C)[(size_t)row * NDIM + col] = f2b(v);
        else          ((float*)C)[(size_t)row * NDIM + col] = v;
      }
    }
  }
}

// ---------------- causal flash attention ----------------
// Q,K: [4096][1024] bf16 (token-major, head h at cols h*64..h*64+63)
// Vt:  [2048][2048] bf16, row = bh*64+dh, col = s
// AO:  [4096][1024] bf16
__global__ __launch_bounds__(256) void k_attn(
    const unsigned short* __restrict__ Qb, const unsigned short* __restrict__ Kb,
    const unsigned short* __restrict__ Vt, unsigned short* __restrict__ AO)
{
  __shared__ unsigned short Plds[4][16*32];
  int qt = blockIdx.x & 31, bh = blockIdx.x >> 5, b = bh >> 4, h = bh & 15;
  int tid = threadIdx.x, w = tid >> 6, lane = tid & 63, l15 = lane & 15, g = lane >> 4;
  int q0 = qt * 64;
  const unsigned short* Qp = Qb + ((size_t)(b*2048 + q0 + w*16)) * 1024 + h*64;
  const unsigned short* Kp = Kb + (size_t)b * 2048 * 1024 + h*64;
  const unsigned short* Vp = Vt + (size_t)bh * 64 * 2048;

  bf16x8 aq[2];
  #pragma unroll
  for (int kk = 0; kk < 2; kk++)
    aq[kk] = *(const bf16x8*)(Qp + (size_t)l15 * 1024 + kk*32 + g*8);

  float m_run[4], l_run[4];
  f32x4 acc_o[4] = {};
  #pragma unroll
  for (int r = 0; r < 4; r++){ m_run[r] = -1e30f; l_run[r] = 0.f; }

  int nt = qt * 2 + 2;
  for (int t = 0; t < nt; ++t){
    int kv0 = t * 32;
    f32x4 s0 = {}, s1 = {};
    #pragma unroll
    for (int kk = 0; kk < 2; kk++){
      bf16x8 bk0 = *(const bf16x8*)(Kp + (size_t)(kv0 + l15) * 1024 + kk*32 + g*8);
      bf16x8 bk1 = *(const bf16x8*)(Kp + (size_t)(kv0 + 16 + l15) * 1024 + kk*32 + g*8);
      s0 = __builtin_amdgcn_mfma_f32_16x16x32_bf16(aq[kk], bk0, s0, 0, 0, 0);
      s1 = __builtin_amdgcn_mfma_f32_16x16x32_bf16(aq[kk], bk1, s1, 0, 0, 0);
    }
    #pragma unroll
    for (int reg = 0; reg < 4; ++reg){
      int row = q0 + w*16 + g*4 + reg;
      int c0 = kv0 + l15, c1 = kv0 + 16 + l15;
      float v0 = s0[reg] * 0.125f; if (c0 > row) v0 = -1e30f;
      float v1 = s1[reg] * 0.125f; if (c1 > row) v1 = -1e30f;
      float mt = fmaxf(v0, v1);
      #pragma unroll
      for (int off = 1; off < 16; off <<= 1) mt = fmaxf(mt, __shfl_xor(mt, off));
      float mn = fmaxf(m_run[reg], mt);
      float corr = __expf(m_run[reg] - mn);
      float p0 = __expf(v0 - mn), p1 = __expf(v1 - mn);
      float ps = p0 + p1;
      #pragma unroll
      for (int off = 1; off < 16; off <<= 1) ps += __shfl_xor(ps, off);
      l_run[reg] = l_run[reg] * corr + ps;
      m_run[reg] = mn;
      #pragma unroll
      for (int ni = 0; ni < 4; ni++) acc_o[ni][reg] *= corr;
      Plds[w][(g*4 + reg)*32 + l15]      = f2b(p0);
      Plds[w][(g*4 + reg)*32 + 16 + l15] = f2b(p1);
    }
    bf16x8 pa = *(const bf16x8*)&Plds[w][l15*32 + g*8];
    #pragma unroll
    for (int ni = 0; ni < 4; ni++){
      bf16x8 bv = *(const bf16x8*)(Vp + (size_t)(ni*16 + l15) * 2048 + kv0 + g*8);
      acc_o[ni] = __builtin_amdgcn_mfma_f32_16x16x32_bf16(pa, bv, acc_o[ni], 0, 0, 0);
    }
  }
  #pragma unroll
  for (int ni = 0; ni < 4; ni++){
    #pragma unroll
    for (int reg = 0; reg < 4; reg++){
      int row = q0 + w*16 + g*4 + reg;
      int dh = ni*16 + l15;
      AO[((size_t)(b*2048 + row)) * 1024 + h*64 + dh] = f2b(acc_o[ni][reg] / l_run[reg]);
    }
  }
}

// ---------------- launch ----------------

extern "C" void kernel_launch(void* const* d_in, const int* in_sizes, int n_in,
                              void* d_out, int out_size, void* d_ws, size_t ws_size,
                              hipStream_t stream){
  const float* x    = (const float*)d_in[0];
  const float* fqk  = (const float*)d_in[1];
  const float* fv   = (const float*)d_in[2];
  const float* rqk  = (const float*)d_in[3];
  const float* rv   = (const float*)d_in[4];
  const float* fwQ  = (const float*)d_in[5];
  const float* fwK  = (const float*)d_in[6];
  const float* fwV  = (const float*)d_in[7];
  const float* rwQ  = (const float*)d_in[8];
  const float* rwK  = (const float*)d_in[9];
  const float* rwV  = (const float*)d_in[10];
  const float* wo   = (const float*)d_in[11];
  float* out = (float*)d_out;

  char* ws = (char*)d_ws;
  size_t off = 0;
  auto alloc = [&](size_t bytes)->void*{
    void* p = ws + off; off += (bytes + 255) & ~(size_t)255; return p;
  };
  unsigned short* Xbf  = (unsigned short*)alloc(4096ull*1024*2);
  unsigned short* FqkT = (unsigned short*)alloc(1024ull*1024*2);
  unsigned short* FvT  = (unsigned short*)alloc(1024ull*1024*2);
  unsigned short* RqkT = (unsigned short*)alloc(1024ull*1024*2);
  unsigned short* RvT  = (unsigned short*)alloc(1024ull*1024*2);
  unsigned short* WOT  = (unsigned short*)alloc(1024ull*1024*2);
  unsigned short* AHqk = (unsigned short*)alloc(4096ull*1024*2);
  unsigned short* AHv  = (unsigned short*)alloc(4096ull*1024*2);
  unsigned short* Gq   = (unsigned short*)alloc(4096ull*1024*2);
  unsigned short* Gk   = (unsigned short*)alloc(4096ull*1024*2);
  unsigned short* Gv   = (unsigned short*)alloc(4096ull*1024*2);
  unsigned short* Qm   = (unsigned short*)alloc(4096ull*1024*2);
  unsigned short* Km   = (unsigned short*)alloc(4096ull*1024*2);
  unsigned short* Vm   = (unsigned short*)alloc(4096ull*1024*2);
  unsigned short* Vtr  = (unsigned short*)alloc(2048ull*2048*2);
  unsigned short* AOm  = (unsigned short*)alloc(4096ull*1024*2);

  // pack/cast
  k_cast_bf16<<<4096, 256, 0, stream>>>(x, Xbf, 4096*1024/4);
  k_transpose_cast<<<4096, 256, 0, stream>>>(fqk, FqkT, 1024, 128, 8*1024*128);
  k_transpose_cast<<<4096, 256, 0, stream>>>(fv,  FvT,  1024, 128, 8*1024*128);
  k_transpose_cast<<<4096, 256, 0, stream>>>(rqk, RqkT, 1024, 1024, 1024*1024);
  k_transpose_cast<<<4096, 256, 0, stream>>>(rv,  RvT,  1024, 1024, 1024*1024);
  k_transpose_cast<<<4096, 256, 0, stream>>>(wo,  WOT,  1024, 1024, 1024*1024);

  // feature GEMMs: all_h = X @ F^T  (2 jobs)
  k_gemm_bt3<1><<<512, 256, 0, stream>>>(Xbf, FqkT, AHqk, Xbf, FvT, AHv,
                                         nullptr, nullptr, nullptr);
  // weighted mix + rank-1 expansion to G matrices
  k_mix_qk<<<4096, 128, 0, stream>>>(AHqk, fwQ, fwK, rwQ, rwK, Gq, Gk);
  k_mix_v <<<4096, 128, 0, stream>>>(AHv, fwV, rwV, Gv);
  // restore GEMMs: Q/K/V = G @ Rflat (3 jobs)
  k_gemm_bt3<1><<<768, 256, 0, stream>>>(Gq, RqkT, Qm, Gk, RqkT, Km, Gv, RvT, Vm);
  // V transpose for PV fragment loads
  k_transpose_v<<<16384, 256, 0, stream>>>(Vm, Vtr);
  // causal flash attention
  k_attn<<<1024, 256, 0, stream>>>(Qm, Km, Vtr, AOm);
  // output projection
  k_gemm_bt3<0><<<256, 256, 0, stream>>>(AOm, WOT, out,
                                         nullptr, nullptr, nullptr,
                                         nullptr, nullptr, nullptr);
}